// Round 21
// baseline (733.306 us; speedup 1.0000x reference)
//
#include <hip/hip_runtime.h>
#include <stdint.h>

#define HH 128
#define H 256
#define W 256
#define KK 51
#define HIMG 306
#define WIMG 306
#define CF 64
#define BB 4
#define HWN (H * W)
#define CHAIN ((size_t)HWN * 64)        // elems per [y][x][64] image

typedef short bhalf8 __attribute__((ext_vector_type(8)));
typedef float f32x4 __attribute__((ext_vector_type(4)));
typedef float f32x16 __attribute__((ext_vector_type(16)));

__device__ inline uint16_t f2bf(float f) {
    uint32_t u = __builtin_bit_cast(uint32_t, f);
    u += 0x7FFF + ((u >> 16) & 1);
    return (uint16_t)(u >> 16);
}
__device__ inline float bf2f(uint16_t h) {
    uint32_t u = ((uint32_t)h) << 16;
    return __builtin_bit_cast(float, u);
}
// 32x32x16 A-fragment: co = m*32 + (lane&31), ci = qq*16 + (lane>>5)*8 + e
__device__ inline bhalf8 aload32(const uint16_t* wp, int k, int tap, int m, int qq, int lane) {
    return *(const bhalf8*)(wp + ((((size_t)(k * 9 + tap) * 2 + m) * 4 + qq) * 64 + lane) * 8);
}
__device__ inline void gload_lds16(const void* g, void* l) {
    __builtin_amdgcn_global_load_lds(
        (const __attribute__((address_space(1))) unsigned int*)g,
        (__attribute__((address_space(3))) unsigned int*)l, 16, 0, 0);
}

// ---------------- fused upsample 2x (align_corners) + cvt, z = batch -----------------
__global__ __launch_bounds__(256) void upsample_cvt(const float* __restrict__ xin,
                                                    uint16_t* __restrict__ upT) {
    const int z = blockIdx.z;
    xin += (size_t)z * CF * HH * HH;
    upT += (size_t)z * CHAIN;
    __shared__ float SU[2][64][19];
    const int y = blockIdx.x, x0 = blockIdx.y * 32;
    const float s = 127.f / 255.f;
    float py = y * s; int ly = (int)py; int hy = min(ly + 1, 127); float wy = py - (float)ly;
    int lx0 = (int)(x0 * s);
    for (int t = threadIdx.x; t < 2 * 64 * 18; t += 256) {
        int col = t % 18; int c = (t / 18) & 63; int row = t / (18 * 64);
        int sy = row ? hy : ly;
        int sx = min(lx0 + col, 127);
        SU[row][c][col] = xin[((size_t)c * 128 + sy) * 128 + sx];
    }
    __syncthreads();
    const int xl = threadIdx.x & 31, cg = threadIdx.x >> 5;
    const int x = x0 + xl;
    float px = x * s; int lx = (int)px; float wx = px - (float)lx;
    int lxl = lx - lx0;
    int hxl = min(lx + 1, 127) - lx0;
    uint32_t d[4];
#pragma unroll
    for (int q4 = 0; q4 < 4; ++q4) {
        uint32_t two[2];
#pragma unroll
        for (int e = 0; e < 2; ++e) {
            int c = cg * 8 + q4 * 2 + e;
            float v00 = SU[0][c][lxl], v01 = SU[0][c][hxl];
            float v10 = SU[1][c][lxl], v11 = SU[1][c][hxl];
            float a = v00 * (1.f - wy) + v10 * wy;
            float b = v01 * (1.f - wy) + v11 * wy;
            two[e] = f2bf(a * (1.f - wx) + b * wx);
        }
        d[q4] = two[0] | (two[1] << 16);
    }
    uint4 v = {d[0], d[1], d[2], d[3]};
    *(uint4*)(upT + ((size_t)y * W + x) * 64 + cg * 8) = v;
}

// ---------------- weight prep: [4][51][CIN][3][3] f32 -> 32x32x16 A-fragment bf16 ---
// dst[k][tap][m(2)][qq(4)][lane(64)][8]; co = m*32+(lane&31), ci = qq*16+(lane>>5)*8+e
__global__ void wprep(const float* __restrict__ wsrc, uint16_t* __restrict__ wdst, int cin_act) {
    int gg = blockIdx.x * 256 + threadIdx.x;   // 4*9*2*4*64 = 18432
    if (gg >= 18432) return;
    int lane = gg & 63;
    int q = gg >> 6;
    int qq = q & 3; q >>= 2;
    int m = q & 1; q >>= 1;
    int tap = q % 9;
    int k = q / 9;
    int co = m * 32 + (lane & 31);
    int ci0 = qq * 16 + (lane >> 5) * 8;
    uint32_t d[4];
#pragma unroll
    for (int p = 0; p < 4; ++p) {
        uint32_t w2[2];
#pragma unroll
        for (int e = 0; e < 2; ++e) {
            int ci = ci0 + p * 2 + e;
            float v = 0.f;
            if (co < KK && ci < cin_act)
                v = wsrc[((size_t)(k * KK + co) * cin_act + ci) * 9 + tap];
            w2[e] = f2bf(v);
        }
        d[p] = w2[0] | (w2[1] << 16);
    }
    uint4 v = {d[0], d[1], d[2], d[3]};
    *(uint4*)(wdst + (size_t)gg * 8) = v;
}

// ---------------- MFMA conv 3x3 + bias + relu: 8-wave, 32x32x16 shape ----------------
// 1D grid of 64*4*NZ blocks (multiple of 8); block 512 = 8 waves.
// tile 4y x 64x x 64co; wave (row = wv&3, xh = wv>>2) owns 4y-row x 32x slab.
// Per K16-step: 1 B ds_read + 2 A loads + 2 MFMA; 36 steps = 72 MFMA/wave.
__global__ __launch_bounds__(512, 4)
void conv_mfma(const uint16_t* __restrict__ in, const uint16_t* __restrict__ wp,
               const float* __restrict__ bias, uint16_t* __restrict__ out,
               size_t in_cstride, size_t in_bstride, int kbase) {
    // bijective XCD swizzle (gridDim.x % 8 == 0 at all call sites)
    const int wg = blockIdx.x;
    const int id = (wg & 7) * ((int)gridDim.x >> 3) + (wg >> 3);
    const int z = id >> 8;              // 256 blocks per z
    const int rem = id & 255;
    const int y0 = (rem & 63) * 4;
    const int x0 = (rem >> 6) * 64;

    const int k = kbase + (z & 3);
    in  += (size_t)(z & 3) * in_cstride + (size_t)(z >> 2) * in_bstride;
    out += (size_t)z * CHAIN;
    const int tid = threadIdx.x;
    const int lane = tid & 63;
    const int wv = tid >> 6;            // 0..7

    __shared__ uint4 lds[6 * 66 * 8];   // 50688 B linear; swizzle lives in the SOURCE addr

    // ---- stage via global_load_lds: lds[q*8+c] <- chunk (c^(xl&7)) of pixel (r, xl)
    unsigned oobmask = 0;
#pragma unroll
    for (int it = 0; it < 7; ++it) {
        int t = tid + it * 512;
        if (t < 6 * 66 * 8) {
            int c = t & 7;
            int q = t >> 3;
            int xl = q % 66;
            int r = q / 66;
            int yg = y0 - 1 + r;
            int xg = x0 + xl - 1;
            if ((unsigned)yg >= H || (unsigned)xg >= W) {
                oobmask |= 1u << it;
                yg = min(max(yg, 0), H - 1);
                xg = min(max(xg, 0), W - 1);
            }
            int cs = c ^ (xl & 7);
            gload_lds16(in + (((size_t)yg * W + xg) * 64 + cs * 8),
                        (char*)lds + ((size_t)it * 512 + wv * 64) * 16);
        }
    }
    asm volatile("s_waitcnt vmcnt(0)" ::: "memory");
#pragma unroll
    for (int it = 0; it < 7; ++it) {
        int t = tid + it * 512;
        if ((oobmask & (1u << it)) && t < 6 * 66 * 8)
            lds[t] = (uint4){0u, 0u, 0u, 0u};
    }
    __syncthreads();

    const int row = wv & 3;             // y-row within tile
    const int xh = wv >> 2;             // x-half (0 or 1), 32 px each
    const int y = y0 + row;
    const int xw = lane & 31;           // x within slab (B/D col)
    const int kgrp = lane >> 5;         // 8-ci subgroup (B k-rows, D +4 row)

    f32x16 acc[2];
#pragma unroll
    for (int m = 0; m < 2; ++m)
#pragma unroll
        for (int r = 0; r < 16; ++r) acc[m][r] = 0.f;

    __builtin_amdgcn_s_setprio(1);
#pragma unroll
    for (int qq = 0; qq < 4; ++qq) {
#pragma unroll
        for (int tap = 0; tap < 9; ++tap) {
            const int ky = tap / 3, kx = tap % 3;
            bhalf8 afr0 = aload32(wp, k, tap, 0, qq, lane);
            bhalf8 afr1 = aload32(wp, k, tap, 1, qq, lane);
            const int rrow = row + ky;
            int xl = xh * 32 + xw + kx;
            int slot = (qq * 2 + kgrp) ^ (xl & 7);
            bhalf8 bfr = *(const bhalf8*)&lds[((size_t)rrow * 66 + xl) * 8 + slot];
            acc[0] = __builtin_amdgcn_mfma_f32_32x32x16_bf16(afr0, bfr, acc[0], 0, 0, 0);
            acc[1] = __builtin_amdgcn_mfma_f32_32x32x16_bf16(afr1, bfr, acc[1], 0, 0, 0);
        }
    }
    __builtin_amdgcn_s_setprio(0);

    // ---- epilogue: bias+relu+pack -> wave-private 4KB tile -> coalesced stores
    // D layout: col(x) = lane&31, row(co in 32) = (reg&3) + 8*(reg>>2) + 4*(lane>>5)
    __syncthreads();                      // all waves done reading staged B
    ushort* ST = (ushort*)lds + wv * 2048;  // 4 KB per wave (reuse staging)
#pragma unroll
    for (int m = 0; m < 2; ++m) {
#pragma unroll
        for (int g4 = 0; g4 < 4; ++g4) {
            int co0 = m * 32 + 8 * g4 + 4 * kgrp;
            float bvr[4];
#pragma unroll
            for (int r = 0; r < 4; ++r)
                bvr[r] = (co0 + r < KK) ? bias[k * KK + co0 + r] : 0.f;
            uint32_t pk[2];
#pragma unroll
            for (int hh = 0; hh < 2; ++hh) {
                uint32_t lo = f2bf(fmaxf(acc[m][4 * g4 + hh * 2]     + bvr[hh * 2],     0.f));
                uint32_t hi = f2bf(fmaxf(acc[m][4 * g4 + hh * 2 + 1] + bvr[hh * 2 + 1], 0.f));
                pk[hh] = lo | (hi << 16);
            }
            int idx = xw * 64 + (co0 ^ ((xw & 7) << 3));
            *(uint2*)(ST + idx) = (uint2){pk[0], pk[1]};
        }
    }
    const int p8 = lane >> 3;
    const int ch = lane & 7;
#pragma unroll
    for (int it = 0; it < 4; ++it) {
        int px = it * 8 + p8;             // 0..31
        uint4 v = *(const uint4*)(ST + px * 64 + ((ch ^ (px & 7)) << 3));
        *(uint4*)(out + (((size_t)y * W + x0 + xh * 32 + px) * 64 + ch * 8)) = v;
    }
}

// ---------------- sepconv via MFMA band-matmul, f32 img staging, z = batch ----------
__global__ __launch_bounds__(256, 2)
void sepconv3(const float* __restrict__ img,
              const uint16_t* __restrict__ kvT, const uint16_t* __restrict__ khT,
              float* __restrict__ out, int accum) {
    __shared__ uint4 SB[320 * 8];
    __shared__ float SC[4][16 * 83];
    const int y = blockIdx.x, c = blockIdx.y, z = blockIdx.z;
    const int tid = threadIdx.x, lane = tid & 63, wv = tid >> 6;
    const float* ip = img + (size_t)(z * 3 + c) * HIMG * WIMG;
    kvT += (size_t)z * 4 * CHAIN;
    khT += (size_t)z * 4 * CHAIN;

    for (int task = tid; task < 40 * 64; task += 256) {
        int i = task & 63;
        int u0 = (task >> 6) * 8;
        float f[8];
        bool rowok = (i <= 50);
        const float* rp = ip + (size_t)(y + i) * WIMG;
#pragma unroll
        for (int e2 = 0; e2 < 4; ++e2) {
            int u = u0 + e2 * 2;
            float2 v2 = (rowok && u < WIMG) ? *(const float2*)(rp + u) : float2{0.f, 0.f};
            f[e2 * 2] = v2.x; f[e2 * 2 + 1] = v2.y;
        }
#pragma unroll
        for (int e = 0; e < 8; ++e) {
            int u = u0 + e;
            *((ushort*)SB + u * 64 + (((i >> 3) ^ (u & 7)) << 3) + (i & 7)) = f2bf(f[e]);
        }
    }
    __syncthreads();

    const int l4 = lane & 15, g = lane >> 4;
    for (int xt = 0; xt < 4; ++xt) {
        const int x0 = (wv * 4 + xt) * 16;
        const int xpix = x0 + l4;
        bhalf8 a0 = *(const bhalf8*)(kvT + ((size_t)y * W + xpix) * 64 + g * 8);
        bhalf8 a1 = *(const bhalf8*)(kvT + ((size_t)y * W + xpix) * 64 + 32 + g * 8);
        f32x4 acc[5];
#pragma unroll
        for (int nt = 0; nt < 5; ++nt) acc[nt] = (f32x4){0.f, 0.f, 0.f, 0.f};
#pragma unroll
        for (int nt = 0; nt < 5; ++nt) {
            int u = x0 + nt * 16 + l4;
            bhalf8 b0 = *(const bhalf8*)((ushort*)SB + u * 64 + ((g ^ (u & 7)) << 3));
            acc[nt] = __builtin_amdgcn_mfma_f32_16x16x32_bf16(a0, b0, acc[nt], 0, 0, 0);
            bhalf8 b1 = *(const bhalf8*)((ushort*)SB + u * 64 + (((4 + g) ^ (u & 7)) << 3));
            acc[nt] = __builtin_amdgcn_mfma_f32_16x16x32_bf16(a1, b1, acc[nt], 0, 0, 0);
        }
#pragma unroll
        for (int nt = 0; nt < 5; ++nt)
#pragma unroll
            for (int r = 0; r < 4; ++r)
                SC[wv][(g * 4 + r) * 83 + nt * 16 + l4] = acc[nt][r];

        const uint16_t* khp = khT + ((size_t)y * W + xpix) * 64;
        float partial = 0.f;
#pragma unroll
        for (int jj = 0; jj < 13; ++jj) {
            int j = g * 13 + jj;
            if (j < KK)
                partial = fmaf(SC[wv][l4 * 83 + l4 + j], bf2f(khp[j]), partial);
        }
        partial += __shfl_xor(partial, 16);
        partial += __shfl_xor(partial, 32);
        if (g == 0) {
            size_t oi = ((size_t)(z * 3 + c) * H + y) * W + xpix;
            if (accum) out[oi] += partial;
            else       out[oi] = partial;
        }
    }
}

extern "C" void kernel_launch(void* const* d_in, const int* in_sizes, int n_in,
                              void* d_out, int out_size, void* d_ws, size_t ws_size,
                              hipStream_t stream) {
    const float* x  = (const float*)d_in[0];
    const float* i1 = (const float*)d_in[1];
    const float* i2 = (const float*)d_in[2];
    const float* W1 = (const float*)d_in[3];
    const float* B1 = (const float*)d_in[4];
    const float* W2 = (const float*)d_in[5];
    const float* B2 = (const float*)d_in[6];
    const float* W3 = (const float*)d_in[7];
    const float* B3 = (const float*)d_in[8];
    float* out = (float*)d_out;

    char* wsb = (char*)d_ws;
    const size_t IMGB = CHAIN * 2;               // 8,388,608 B per bf16 image
    const size_t WPN  = 18432 * 8;               // elems per wp layer

    // weight-prep tables live in d_out (884,736 B << 3.1 MB); fully consumed by the conv
    // layers before sepconv overwrites d_out (stream-ordered, race-free).
    uint16_t* wp1 = (uint16_t*)d_out;
    uint16_t* wp2 = wp1 + WPN;
    uint16_t* wp3 = wp2 + WPN;
    wprep<<<72, 256, 0, stream>>>(W1, wp1, CF);
    wprep<<<72, 256, 0, stream>>>(W2, wp2, KK);
    wprep<<<72, 256, 0, stream>>>(W3, wp3, KK);

    if (ws_size >= 32 * IMGB) {
        // ---- fully batch-merged: A/B ping-pong of 16 images each (exactly 256 MiB)
        uint16_t* A   = (uint16_t*)wsb;
        uint16_t* Bb  = (uint16_t*)(wsb + 16 * IMGB);
        uint16_t* upT = Bb + 12 * CHAIN;         // upT in B[12..16), dead after layer 1

        upsample_cvt<<<dim3(H, 8, BB), 256, 0, stream>>>(x, upT);
        conv_mfma<<<dim3(64 * 4 * 16), 512, 0, stream>>>(upT, wp1, B1, A, 0, CHAIN, 0);
        conv_mfma<<<dim3(64 * 4 * 16), 512, 0, stream>>>(A,  wp2, B2, Bb, CHAIN, 4 * CHAIN, 0);
        conv_mfma<<<dim3(64 * 4 * 16), 512, 0, stream>>>(Bb, wp3, B3, A,  CHAIN, 4 * CHAIN, 0);
        sepconv3<<<dim3(H, 3, BB), 256, 0, stream>>>(i1, A,             A + CHAIN,     out, 0);
        sepconv3<<<dim3(H, 3, BB), 256, 0, stream>>>(i2, A + 2 * CHAIN, A + 3 * CHAIN, out, 1);
    } else if (ws_size >= 13 * IMGB) {
        // ---- per-batch fallback (109 MB)
        uint16_t* r1  = (uint16_t*)wsb;
        uint16_t* r2  = (uint16_t*)(wsb + 4 * IMGB);
        uint16_t* r3  = (uint16_t*)(wsb + 8 * IMGB);
        uint16_t* upT = (uint16_t*)(wsb + 12 * IMGB);
        for (int b = 0; b < BB; ++b) {
            upsample_cvt<<<dim3(H, 8, 1), 256, 0, stream>>>(x + (size_t)b * CF * HH * HH, upT);
            conv_mfma<<<dim3(64 * 4 * 4), 512, 0, stream>>>(upT, wp1, B1, r1, 0, 0, 0);
            conv_mfma<<<dim3(64 * 4 * 4), 512, 0, stream>>>(r1, wp2, B2, r2, CHAIN, 0, 0);
            conv_mfma<<<dim3(64 * 4 * 4), 512, 0, stream>>>(r2, wp3, B3, r3, CHAIN, 0, 0);
            for (int p = 0; p < 2; ++p) {
                const float* img = (p ? i2 : i1) + (size_t)b * 3 * HIMG * WIMG;
                sepconv3<<<dim3(H, 3, 1), 256, 0, stream>>>(img,
                        r3 + (size_t)(2 * p) * CHAIN, r3 + (size_t)(2 * p + 1) * CHAIN,
                        out + (size_t)b * 3 * HWN, p);
            }
        }
    } else {
        // ---- minimal (59 MB): per (batch, phase), 2-chain dispatches
        uint16_t* upT = (uint16_t*)wsb;
        uint16_t* t1  = (uint16_t*)(wsb + 1 * IMGB);
        uint16_t* t2  = (uint16_t*)(wsb + 3 * IMGB);
        uint16_t* t3  = (uint16_t*)(wsb + 5 * IMGB);
        for (int b = 0; b < BB; ++b) {
            upsample_cvt<<<dim3(H, 8, 1), 256, 0, stream>>>(x + (size_t)b * CF * HH * HH, upT);
            for (int p = 0; p < 2; ++p) {
                conv_mfma<<<dim3(64 * 4 * 2), 512, 0, stream>>>(upT, wp1, B1, t1, 0, 0, 2 * p);
                conv_mfma<<<dim3(64 * 4 * 2), 512, 0, stream>>>(t1, wp2, B2, t2, CHAIN, 0, 2 * p);
                conv_mfma<<<dim3(64 * 4 * 2), 512, 0, stream>>>(t2, wp3, B3, t3, CHAIN, 0, 2 * p);
                const float* img = (p ? i2 : i1) + (size_t)b * 3 * HIMG * WIMG;
                sepconv3<<<dim3(H, 3, 1), 256, 0, stream>>>(img, t3, t3 + CHAIN,
                        out + (size_t)b * 3 * HWN, p);
            }
        }
    }
}

// Round 22
// 513.096 us; speedup vs baseline: 1.4292x; 1.4292x over previous
//
#include <hip/hip_runtime.h>
#include <stdint.h>

#define HH 128
#define H 256
#define W 256
#define KK 51
#define HIMG 306
#define WIMG 306
#define CF 64
#define BB 4
#define HWN (H * W)
#define CHAIN ((size_t)HWN * 64)        // elems per [y][x][64] image

typedef short bhalf8 __attribute__((ext_vector_type(8)));
typedef float f32x4 __attribute__((ext_vector_type(4)));

__device__ inline uint16_t f2bf(float f) {
    uint32_t u = __builtin_bit_cast(uint32_t, f);
    u += 0x7FFF + ((u >> 16) & 1);
    return (uint16_t)(u >> 16);
}
__device__ inline float bf2f(uint16_t h) {
    uint32_t u = ((uint32_t)h) << 16;
    return __builtin_bit_cast(float, u);
}
__device__ inline bhalf8 aload(const uint16_t* wp, int k, int tap, int m, int chf, int lane) {
    return *(const bhalf8*)(wp + ((((size_t)(k * 9 + tap) * 4 + m) * 2 + chf) * 64 + lane) * 8);
}
__device__ inline void gload_lds16(const void* g, void* l) {
    __builtin_amdgcn_global_load_lds(
        (const __attribute__((address_space(1))) unsigned int*)g,
        (__attribute__((address_space(3))) unsigned int*)l, 16, 0, 0);
}

// ---------------- fused upsample 2x (align_corners) + cvt, z = batch -----------------
__global__ __launch_bounds__(256) void upsample_cvt(const float* __restrict__ xin,
                                                    uint16_t* __restrict__ upT) {
    const int z = blockIdx.z;
    xin += (size_t)z * CF * HH * HH;
    upT += (size_t)z * CHAIN;
    __shared__ float SU[2][64][19];
    const int y = blockIdx.x, x0 = blockIdx.y * 32;
    const float s = 127.f / 255.f;
    float py = y * s; int ly = (int)py; int hy = min(ly + 1, 127); float wy = py - (float)ly;
    int lx0 = (int)(x0 * s);
    for (int t = threadIdx.x; t < 2 * 64 * 18; t += 256) {
        int col = t % 18; int c = (t / 18) & 63; int row = t / (18 * 64);
        int sy = row ? hy : ly;
        int sx = min(lx0 + col, 127);
        SU[row][c][col] = xin[((size_t)c * 128 + sy) * 128 + sx];
    }
    __syncthreads();
    const int xl = threadIdx.x & 31, cg = threadIdx.x >> 5;
    const int x = x0 + xl;
    float px = x * s; int lx = (int)px; float wx = px - (float)lx;
    int lxl = lx - lx0;
    int hxl = min(lx + 1, 127) - lx0;
    uint32_t d[4];
#pragma unroll
    for (int q4 = 0; q4 < 4; ++q4) {
        uint32_t two[2];
#pragma unroll
        for (int e = 0; e < 2; ++e) {
            int c = cg * 8 + q4 * 2 + e;
            float v00 = SU[0][c][lxl], v01 = SU[0][c][hxl];
            float v10 = SU[1][c][lxl], v11 = SU[1][c][hxl];
            float a = v00 * (1.f - wy) + v10 * wy;
            float b = v01 * (1.f - wy) + v11 * wy;
            two[e] = f2bf(a * (1.f - wx) + b * wx);
        }
        d[q4] = two[0] | (two[1] << 16);
    }
    uint4 v = {d[0], d[1], d[2], d[3]};
    *(uint4*)(upT + ((size_t)y * W + x) * 64 + cg * 8) = v;
}

// ---------------- weight prep: [4][51][CIN][3][3] f32 -> A-fragment order bf16 ------
__global__ void wprep(const float* __restrict__ wsrc, uint16_t* __restrict__ wdst, int cin_act) {
    int g = blockIdx.x * 256 + threadIdx.x;
    if (g >= 4 * 9 * 4 * 2 * 64) return;
    int lane = g & 63;
    int q = g >> 6;
    int ch = q & 1; q >>= 1;
    int m = q & 3; q >>= 2;
    int tap = q % 9;
    int k = q / 9;
    int co = m * 16 + (lane & 15);
    int ci0 = ch * 32 + (lane >> 4) * 8;
    uint32_t d[4];
#pragma unroll
    for (int p = 0; p < 4; ++p) {
        uint32_t w2[2];
#pragma unroll
        for (int e = 0; e < 2; ++e) {
            int ci = ci0 + p * 2 + e;
            float v = 0.f;
            if (co < KK && ci < cin_act)
                v = wsrc[((size_t)(k * KK + co) * cin_act + ci) * 9 + tap];
            w2[e] = f2bf(v);
        }
        d[p] = w2[0] | (w2[1] << 16);
    }
    uint4 v = {d[0], d[1], d[2], d[3]};
    *(uint4*)(wdst + (size_t)g * 8) = v;
}

// ---------------- MFMA conv 3x3 + bias + relu: 8-wave, acc-halved (r15/r20 proven) ---
// 1D grid of 64*4*NZ blocks (multiple of 8); block 512 = 8 waves.
// tile 4y x 64x x 64co; wave (row = wv&3, nh = (wv>>2)*2) owns 4y-row x 32x slab.
__global__ __launch_bounds__(512, 4)
void conv_mfma(const uint16_t* __restrict__ in, const uint16_t* __restrict__ wp,
               const float* __restrict__ bias, uint16_t* __restrict__ out,
               size_t in_cstride, size_t in_bstride, int kbase) {
    // bijective XCD swizzle (gridDim.x % 8 == 0 at all call sites)
    const int wg = blockIdx.x;
    const int id = (wg & 7) * ((int)gridDim.x >> 3) + (wg >> 3);
    const int z = id >> 8;              // 256 blocks per z
    const int rem = id & 255;
    const int y0 = (rem & 63) * 4;
    const int x0 = (rem >> 6) * 64;

    const int k = kbase + (z & 3);
    in  += (size_t)(z & 3) * in_cstride + (size_t)(z >> 2) * in_bstride;
    out += (size_t)z * CHAIN;
    const int tid = threadIdx.x;
    const int lane = tid & 63;
    const int wv = tid >> 6;            // 0..7
    const int l4 = lane & 15, g = lane >> 4;

    __shared__ uint4 lds[6 * 66 * 8];   // 50688 B linear; swizzle lives in the SOURCE addr

    // ---- stage via global_load_lds: lds[q*8+c] <- chunk (c^(xl&7)) of pixel (r, xl)
    unsigned oobmask = 0;
#pragma unroll
    for (int it = 0; it < 7; ++it) {
        int t = tid + it * 512;
        if (t < 6 * 66 * 8) {
            int c = t & 7;
            int q = t >> 3;
            int xl = q % 66;
            int r = q / 66;
            int yg = y0 - 1 + r;
            int xg = x0 + xl - 1;
            if ((unsigned)yg >= H || (unsigned)xg >= W) {
                oobmask |= 1u << it;
                yg = min(max(yg, 0), H - 1);
                xg = min(max(xg, 0), W - 1);
            }
            int cs = c ^ (xl & 7);
            gload_lds16(in + (((size_t)yg * W + xg) * 64 + cs * 8),
                        (char*)lds + ((size_t)it * 512 + wv * 64) * 16);
        }
    }
    asm volatile("s_waitcnt vmcnt(0)" ::: "memory");
#pragma unroll
    for (int it = 0; it < 7; ++it) {
        int t = tid + it * 512;
        if ((oobmask & (1u << it)) && t < 6 * 66 * 8)
            lds[t] = (uint4){0u, 0u, 0u, 0u};
    }
    __syncthreads();

    const int row = wv & 3;             // y-row within tile
    const int nh = (wv >> 2) * 2;       // first n-tile (0 or 2)
    const int y = y0 + row;

    f32x4 acc[4][2];
#pragma unroll
    for (int m = 0; m < 4; ++m)
#pragma unroll
        for (int nn = 0; nn < 2; ++nn)
            acc[m][nn] = (f32x4){0.f, 0.f, 0.f, 0.f};

    __builtin_amdgcn_s_setprio(1);
#pragma unroll
    for (int chf = 0; chf < 2; ++chf) {
#pragma unroll
        for (int tap = 0; tap < 9; ++tap) {
            const int ky = tap / 3, kx = tap % 3;
            bhalf8 afr[4];
#pragma unroll
            for (int m = 0; m < 4; ++m) afr[m] = aload(wp, k, tap, m, chf, lane);
            const int rrow = row + ky;
#pragma unroll
            for (int nn = 0; nn < 2; ++nn) {
                int xl = (nh + nn) * 16 + l4 + kx;
                int slot = (chf * 4 + g) ^ (xl & 7);
                bhalf8 bfr = *(const bhalf8*)&lds[((size_t)rrow * 66 + xl) * 8 + slot];
#pragma unroll
                for (int m = 0; m < 4; ++m)
                    acc[m][nn] = __builtin_amdgcn_mfma_f32_16x16x32_bf16(afr[m], bfr, acc[m][nn], 0, 0, 0);
            }
        }
    }
    __builtin_amdgcn_s_setprio(0);

    // ---- epilogue: bias+relu+pack -> wave-private 4KB tile -> coalesced stores
    __syncthreads();                      // all waves done reading staged B
    ushort* ST = (ushort*)lds + wv * 2048;  // 4 KB per wave (reuse staging)
#pragma unroll
    for (int m = 0; m < 4; ++m) {
        int co0 = m * 16 + g * 4;
        float bvr[4];
#pragma unroll
        for (int r = 0; r < 4; ++r)
            bvr[r] = (co0 + r < KK) ? bias[k * KK + co0 + r] : 0.f;
#pragma unroll
        for (int nn = 0; nn < 2; ++nn) {
            int pxl = nn * 16 + l4;       // 0..31 within wave's slab
            uint32_t pk[2];
#pragma unroll
            for (int hh = 0; hh < 2; ++hh) {
                uint32_t lo = f2bf(fmaxf(acc[m][nn][hh * 2]     + bvr[hh * 2],     0.f));
                uint32_t hi = f2bf(fmaxf(acc[m][nn][hh * 2 + 1] + bvr[hh * 2 + 1], 0.f));
                pk[hh] = lo | (hi << 16);
            }
            int idx = pxl * 64 + (co0 ^ ((pxl & 7) << 3));
            *(uint2*)(ST + idx) = (uint2){pk[0], pk[1]};
        }
    }
    const int p8 = lane >> 3;
    const int ch = lane & 7;
#pragma unroll
    for (int it = 0; it < 4; ++it) {
        int px = it * 8 + p8;             // 0..31
        uint4 v = *(const uint4*)(ST + px * 64 + ((ch ^ (px & 7)) << 3));
        *(uint4*)(out + (((size_t)y * W + x0 + nh * 16 + px) * 64 + ch * 8)) = v;
    }
}

// ---------------- sepconv via MFMA band-matmul, f32 img staging, z = batch ----------
__global__ __launch_bounds__(256, 2)
void sepconv3(const float* __restrict__ img,
              const uint16_t* __restrict__ kvT, const uint16_t* __restrict__ khT,
              float* __restrict__ out, int accum) {
    __shared__ uint4 SB[320 * 8];
    __shared__ float SC[4][16 * 83];
    const int y = blockIdx.x, c = blockIdx.y, z = blockIdx.z;
    const int tid = threadIdx.x, lane = tid & 63, wv = tid >> 6;
    const float* ip = img + (size_t)(z * 3 + c) * HIMG * WIMG;
    kvT += (size_t)z * 4 * CHAIN;
    khT += (size_t)z * 4 * CHAIN;

    for (int task = tid; task < 40 * 64; task += 256) {
        int i = task & 63;
        int u0 = (task >> 6) * 8;
        float f[8];
        bool rowok = (i <= 50);
        const float* rp = ip + (size_t)(y + i) * WIMG;
#pragma unroll
        for (int e2 = 0; e2 < 4; ++e2) {
            int u = u0 + e2 * 2;
            float2 v2 = (rowok && u < WIMG) ? *(const float2*)(rp + u) : float2{0.f, 0.f};
            f[e2 * 2] = v2.x; f[e2 * 2 + 1] = v2.y;
        }
#pragma unroll
        for (int e = 0; e < 8; ++e) {
            int u = u0 + e;
            *((ushort*)SB + u * 64 + (((i >> 3) ^ (u & 7)) << 3) + (i & 7)) = f2bf(f[e]);
        }
    }
    __syncthreads();

    const int l4 = lane & 15, g = lane >> 4;
    for (int xt = 0; xt < 4; ++xt) {
        const int x0 = (wv * 4 + xt) * 16;
        const int xpix = x0 + l4;
        bhalf8 a0 = *(const bhalf8*)(kvT + ((size_t)y * W + xpix) * 64 + g * 8);
        bhalf8 a1 = *(const bhalf8*)(kvT + ((size_t)y * W + xpix) * 64 + 32 + g * 8);
        f32x4 acc[5];
#pragma unroll
        for (int nt = 0; nt < 5; ++nt) acc[nt] = (f32x4){0.f, 0.f, 0.f, 0.f};
#pragma unroll
        for (int nt = 0; nt < 5; ++nt) {
            int u = x0 + nt * 16 + l4;
            bhalf8 b0 = *(const bhalf8*)((ushort*)SB + u * 64 + ((g ^ (u & 7)) << 3));
            acc[nt] = __builtin_amdgcn_mfma_f32_16x16x32_bf16(a0, b0, acc[nt], 0, 0, 0);
            bhalf8 b1 = *(const bhalf8*)((ushort*)SB + u * 64 + (((4 + g) ^ (u & 7)) << 3));
            acc[nt] = __builtin_amdgcn_mfma_f32_16x16x32_bf16(a1, b1, acc[nt], 0, 0, 0);
        }
#pragma unroll
        for (int nt = 0; nt < 5; ++nt)
#pragma unroll
            for (int r = 0; r < 4; ++r)
                SC[wv][(g * 4 + r) * 83 + nt * 16 + l4] = acc[nt][r];

        const uint16_t* khp = khT + ((size_t)y * W + xpix) * 64;
        float partial = 0.f;
#pragma unroll
        for (int jj = 0; jj < 13; ++jj) {
            int j = g * 13 + jj;
            if (j < KK)
                partial = fmaf(SC[wv][l4 * 83 + l4 + j], bf2f(khp[j]), partial);
        }
        partial += __shfl_xor(partial, 16);
        partial += __shfl_xor(partial, 32);
        if (g == 0) {
            size_t oi = ((size_t)(z * 3 + c) * H + y) * W + xpix;
            if (accum) out[oi] += partial;
            else       out[oi] = partial;
        }
    }
}

extern "C" void kernel_launch(void* const* d_in, const int* in_sizes, int n_in,
                              void* d_out, int out_size, void* d_ws, size_t ws_size,
                              hipStream_t stream) {
    const float* x  = (const float*)d_in[0];
    const float* i1 = (const float*)d_in[1];
    const float* i2 = (const float*)d_in[2];
    const float* W1 = (const float*)d_in[3];
    const float* B1 = (const float*)d_in[4];
    const float* W2 = (const float*)d_in[5];
    const float* B2 = (const float*)d_in[6];
    const float* W3 = (const float*)d_in[7];
    const float* B3 = (const float*)d_in[8];
    float* out = (float*)d_out;

    char* wsb = (char*)d_ws;
    const size_t IMGB = CHAIN * 2;               // 8,388,608 B per bf16 image
    const size_t WPN  = 4 * 9 * 4 * 2 * 64 * 8;  // elems per wp layer

    // weight-prep tables live in d_out (884,736 B << 3.1 MB); fully consumed by the conv
    // layers before sepconv overwrites d_out (stream-ordered, race-free).
    uint16_t* wp1 = (uint16_t*)d_out;
    uint16_t* wp2 = wp1 + WPN;
    uint16_t* wp3 = wp2 + WPN;
    wprep<<<72, 256, 0, stream>>>(W1, wp1, CF);
    wprep<<<72, 256, 0, stream>>>(W2, wp2, KK);
    wprep<<<72, 256, 0, stream>>>(W3, wp3, KK);

    if (ws_size >= 32 * IMGB) {
        // ---- fully batch-merged: A/B ping-pong of 16 images each (exactly 256 MiB)
        uint16_t* A   = (uint16_t*)wsb;
        uint16_t* Bb  = (uint16_t*)(wsb + 16 * IMGB);
        uint16_t* upT = Bb + 12 * CHAIN;         // upT in B[12..16), dead after layer 1

        upsample_cvt<<<dim3(H, 8, BB), 256, 0, stream>>>(x, upT);
        conv_mfma<<<dim3(64 * 4 * 16), 512, 0, stream>>>(upT, wp1, B1, A, 0, CHAIN, 0);
        conv_mfma<<<dim3(64 * 4 * 16), 512, 0, stream>>>(A,  wp2, B2, Bb, CHAIN, 4 * CHAIN, 0);
        conv_mfma<<<dim3(64 * 4 * 16), 512, 0, stream>>>(Bb, wp3, B3, A,  CHAIN, 4 * CHAIN, 0);
        sepconv3<<<dim3(H, 3, BB), 256, 0, stream>>>(i1, A,             A + CHAIN,     out, 0);
        sepconv3<<<dim3(H, 3, BB), 256, 0, stream>>>(i2, A + 2 * CHAIN, A + 3 * CHAIN, out, 1);
    } else if (ws_size >= 13 * IMGB) {
        // ---- per-batch fallback (109 MB)
        uint16_t* r1  = (uint16_t*)wsb;
        uint16_t* r2  = (uint16_t*)(wsb + 4 * IMGB);
        uint16_t* r3  = (uint16_t*)(wsb + 8 * IMGB);
        uint16_t* upT = (uint16_t*)(wsb + 12 * IMGB);
        for (int b = 0; b < BB; ++b) {
            upsample_cvt<<<dim3(H, 8, 1), 256, 0, stream>>>(x + (size_t)b * CF * HH * HH, upT);
            conv_mfma<<<dim3(64 * 4 * 4), 512, 0, stream>>>(upT, wp1, B1, r1, 0, 0, 0);
            conv_mfma<<<dim3(64 * 4 * 4), 512, 0, stream>>>(r1, wp2, B2, r2, CHAIN, 0, 0);
            conv_mfma<<<dim3(64 * 4 * 4), 512, 0, stream>>>(r2, wp3, B3, r3, CHAIN, 0, 0);
            for (int p = 0; p < 2; ++p) {
                const float* img = (p ? i2 : i1) + (size_t)b * 3 * HIMG * WIMG;
                sepconv3<<<dim3(H, 3, 1), 256, 0, stream>>>(img,
                        r3 + (size_t)(2 * p) * CHAIN, r3 + (size_t)(2 * p + 1) * CHAIN,
                        out + (size_t)b * 3 * HWN, p);
            }
        }
    } else {
        // ---- minimal (59 MB): per (batch, phase), 2-chain dispatches
        uint16_t* upT = (uint16_t*)wsb;
        uint16_t* t1  = (uint16_t*)(wsb + 1 * IMGB);
        uint16_t* t2  = (uint16_t*)(wsb + 3 * IMGB);
        uint16_t* t3  = (uint16_t*)(wsb + 5 * IMGB);
        for (int b = 0; b < BB; ++b) {
            upsample_cvt<<<dim3(H, 8, 1), 256, 0, stream>>>(x + (size_t)b * CF * HH * HH, upT);
            for (int p = 0; p < 2; ++p) {
                conv_mfma<<<dim3(64 * 4 * 2), 512, 0, stream>>>(upT, wp1, B1, t1, 0, 0, 2 * p);
                conv_mfma<<<dim3(64 * 4 * 2), 512, 0, stream>>>(t1, wp2, B2, t2, CHAIN, 0, 2 * p);
                conv_mfma<<<dim3(64 * 4 * 2), 512, 0, stream>>>(t2, wp3, B3, t3, CHAIN, 0, 2 * p);
                const float* img = (p ? i2 : i1) + (size_t)b * 3 * HIMG * WIMG;
                sepconv3<<<dim3(H, 3, 1), 256, 0, stream>>>(img, t3, t3 + CHAIN,
                        out + (size_t)b * 3 * HWN, p);
            }
        }
    }
}

// Round 23
// 499.914 us; speedup vs baseline: 1.4669x; 1.0264x over previous
//
#include <hip/hip_runtime.h>
#include <stdint.h>

#define HH 128
#define H 256
#define W 256
#define KK 51
#define HIMG 306
#define WIMG 306
#define CF 64
#define BB 4
#define HWN (H * W)
#define CHAIN ((size_t)HWN * 64)        // elems per [y][x][64] image

typedef short bhalf8 __attribute__((ext_vector_type(8)));
typedef float f32x4 __attribute__((ext_vector_type(4)));

__device__ inline uint16_t f2bf(float f) {
    uint32_t u = __builtin_bit_cast(uint32_t, f);
    u += 0x7FFF + ((u >> 16) & 1);
    return (uint16_t)(u >> 16);
}
__device__ inline float bf2f(uint16_t h) {
    uint32_t u = ((uint32_t)h) << 16;
    return __builtin_bit_cast(float, u);
}
__device__ inline bhalf8 aload(const uint16_t* wp, int k, int tap, int m, int chf, int lane) {
    return *(const bhalf8*)(wp + ((((size_t)(k * 9 + tap) * 4 + m) * 2 + chf) * 64 + lane) * 8);
}
__device__ inline void gload_lds16(const void* g, void* l) {
    __builtin_amdgcn_global_load_lds(
        (const __attribute__((address_space(1))) unsigned int*)g,
        (__attribute__((address_space(3))) unsigned int*)l, 16, 0, 0);
}

// ---------------- fused upsample 2x (align_corners) + cvt, z = batch -----------------
__global__ __launch_bounds__(256) void upsample_cvt(const float* __restrict__ xin,
                                                    uint16_t* __restrict__ upT) {
    const int z = blockIdx.z;
    xin += (size_t)z * CF * HH * HH;
    upT += (size_t)z * CHAIN;
    __shared__ float SU[2][64][19];
    const int y = blockIdx.x, x0 = blockIdx.y * 32;
    const float s = 127.f / 255.f;
    float py = y * s; int ly = (int)py; int hy = min(ly + 1, 127); float wy = py - (float)ly;
    int lx0 = (int)(x0 * s);
    for (int t = threadIdx.x; t < 2 * 64 * 18; t += 256) {
        int col = t % 18; int c = (t / 18) & 63; int row = t / (18 * 64);
        int sy = row ? hy : ly;
        int sx = min(lx0 + col, 127);
        SU[row][c][col] = xin[((size_t)c * 128 + sy) * 128 + sx];
    }
    __syncthreads();
    const int xl = threadIdx.x & 31, cg = threadIdx.x >> 5;
    const int x = x0 + xl;
    float px = x * s; int lx = (int)px; float wx = px - (float)lx;
    int lxl = lx - lx0;
    int hxl = min(lx + 1, 127) - lx0;
    uint32_t d[4];
#pragma unroll
    for (int q4 = 0; q4 < 4; ++q4) {
        uint32_t two[2];
#pragma unroll
        for (int e = 0; e < 2; ++e) {
            int c = cg * 8 + q4 * 2 + e;
            float v00 = SU[0][c][lxl], v01 = SU[0][c][hxl];
            float v10 = SU[1][c][lxl], v11 = SU[1][c][hxl];
            float a = v00 * (1.f - wy) + v10 * wy;
            float b = v01 * (1.f - wy) + v11 * wy;
            two[e] = f2bf(a * (1.f - wx) + b * wx);
        }
        d[q4] = two[0] | (two[1] << 16);
    }
    uint4 v = {d[0], d[1], d[2], d[3]};
    *(uint4*)(upT + ((size_t)y * W + x) * 64 + cg * 8) = v;
}

// ---------------- weight prep: [4][51][CIN][3][3] f32 -> A-fragment order bf16 ------
__global__ void wprep(const float* __restrict__ wsrc, uint16_t* __restrict__ wdst, int cin_act) {
    int g = blockIdx.x * 256 + threadIdx.x;
    if (g >= 4 * 9 * 4 * 2 * 64) return;
    int lane = g & 63;
    int q = g >> 6;
    int ch = q & 1; q >>= 1;
    int m = q & 3; q >>= 2;
    int tap = q % 9;
    int k = q / 9;
    int co = m * 16 + (lane & 15);
    int ci0 = ch * 32 + (lane >> 4) * 8;
    uint32_t d[4];
#pragma unroll
    for (int p = 0; p < 4; ++p) {
        uint32_t w2[2];
#pragma unroll
        for (int e = 0; e < 2; ++e) {
            int ci = ci0 + p * 2 + e;
            float v = 0.f;
            if (co < KK && ci < cin_act)
                v = wsrc[((size_t)(k * KK + co) * cin_act + ci) * 9 + tap];
            w2[e] = f2bf(v);
        }
        d[p] = w2[0] | (w2[1] << 16);
    }
    uint4 v = {d[0], d[1], d[2], d[3]};
    *(uint4*)(wdst + (size_t)g * 8) = v;
}

// ---------------- MFMA conv 3x3 + bias + relu: 8-wave, co-split decomposition --------
// 1D grid of 64*4*NZ blocks (mult of 8); block 512 = 8 waves; tile 4y x 64x x 64co.
// Wave (row = wv&3, mh = wv>>2) computes 2 co-groups x all 64 x: halves redundant
// A-fragment L1/L2 traffic (8x -> 4x) at the cost of 2x LDS B-reads (still hidden).
__global__ __launch_bounds__(512, 4)
void conv_mfma(const uint16_t* __restrict__ in, const uint16_t* __restrict__ wp,
               const float* __restrict__ bias, uint16_t* __restrict__ out,
               size_t in_cstride, size_t in_bstride, int kbase) {
    // bijective XCD swizzle (gridDim.x % 8 == 0 at all call sites)
    const int wg = blockIdx.x;
    const int id = (wg & 7) * ((int)gridDim.x >> 3) + (wg >> 3);
    const int z = id >> 8;              // 256 blocks per z
    const int rem = id & 255;
    const int y0 = (rem & 63) * 4;
    const int x0 = (rem >> 6) * 64;

    const int k = kbase + (z & 3);
    in  += (size_t)(z & 3) * in_cstride + (size_t)(z >> 2) * in_bstride;
    out += (size_t)z * CHAIN;
    const int tid = threadIdx.x;
    const int lane = tid & 63;
    const int wv = tid >> 6;            // 0..7
    const int l4 = lane & 15, g = lane >> 4;

    __shared__ uint4 lds[6 * 66 * 8];   // 50688 B linear; swizzle lives in the SOURCE addr

    // ---- stage via global_load_lds: lds[q*8+c] <- chunk (c^(xl&7)) of pixel (r, xl)
    unsigned oobmask = 0;
#pragma unroll
    for (int it = 0; it < 7; ++it) {
        int t = tid + it * 512;
        if (t < 6 * 66 * 8) {
            int c = t & 7;
            int q = t >> 3;
            int xl = q % 66;
            int r = q / 66;
            int yg = y0 - 1 + r;
            int xg = x0 + xl - 1;
            if ((unsigned)yg >= H || (unsigned)xg >= W) {
                oobmask |= 1u << it;
                yg = min(max(yg, 0), H - 1);
                xg = min(max(xg, 0), W - 1);
            }
            int cs = c ^ (xl & 7);
            gload_lds16(in + (((size_t)yg * W + xg) * 64 + cs * 8),
                        (char*)lds + ((size_t)it * 512 + wv * 64) * 16);
        }
    }
    asm volatile("s_waitcnt vmcnt(0)" ::: "memory");
#pragma unroll
    for (int it = 0; it < 7; ++it) {
        int t = tid + it * 512;
        if ((oobmask & (1u << it)) && t < 6 * 66 * 8)
            lds[t] = (uint4){0u, 0u, 0u, 0u};
    }
    __syncthreads();

    const int row = wv & 3;             // y-row within tile
    const int mh = wv >> 2;             // co-half (0 or 1): m = mh*2 + ml
    const int y = y0 + row;

    f32x4 acc[2][4];                    // [ml][nn], 32 VGPR
#pragma unroll
    for (int ml = 0; ml < 2; ++ml)
#pragma unroll
        for (int nn = 0; nn < 4; ++nn)
            acc[ml][nn] = (f32x4){0.f, 0.f, 0.f, 0.f};

    __builtin_amdgcn_s_setprio(1);
#pragma unroll
    for (int chf = 0; chf < 2; ++chf) {
#pragma unroll
        for (int tap = 0; tap < 9; ++tap) {
            const int ky = tap / 3, kx = tap % 3;
            bhalf8 afr[2];
#pragma unroll
            for (int ml = 0; ml < 2; ++ml)
                afr[ml] = aload(wp, k, tap, mh * 2 + ml, chf, lane);
            const int rrow = row + ky;
#pragma unroll
            for (int nn = 0; nn < 4; ++nn) {
                int xl = nn * 16 + l4 + kx;
                int slot = (chf * 4 + g) ^ (xl & 7);
                bhalf8 bfr = *(const bhalf8*)&lds[((size_t)rrow * 66 + xl) * 8 + slot];
#pragma unroll
                for (int ml = 0; ml < 2; ++ml)
                    acc[ml][nn] = __builtin_amdgcn_mfma_f32_16x16x32_bf16(afr[ml], bfr, acc[ml][nn], 0, 0, 0);
            }
        }
    }
    __builtin_amdgcn_s_setprio(0);

    // ---- epilogue: bias+relu+pack -> shared per-row 8KB tile (2 waves fill disjoint
    // co-halves) -> coalesced 1KB-contiguous stores (proven pattern).
    __syncthreads();                      // all waves done reading staged B
    ushort* RT = (ushort*)lds + row * 4096;  // 8 KB per row-tile, 32 KB total
#pragma unroll
    for (int ml = 0; ml < 2; ++ml) {
        int co0 = (mh * 2 + ml) * 16 + g * 4;
        float bvr[4];
#pragma unroll
        for (int r = 0; r < 4; ++r)
            bvr[r] = (co0 + r < KK) ? bias[k * KK + co0 + r] : 0.f;
#pragma unroll
        for (int nn = 0; nn < 4; ++nn) {
            int pxl = nn * 16 + l4;       // 0..63
            uint32_t pk[2];
#pragma unroll
            for (int hh = 0; hh < 2; ++hh) {
                uint32_t lo = f2bf(fmaxf(acc[ml][nn][hh * 2]     + bvr[hh * 2],     0.f));
                uint32_t hi = f2bf(fmaxf(acc[ml][nn][hh * 2 + 1] + bvr[hh * 2 + 1], 0.f));
                pk[hh] = lo | (hi << 16);
            }
            int idx = pxl * 64 + (co0 ^ ((pxl & 7) << 3));
            *(uint2*)(RT + idx) = (uint2){pk[0], pk[1]};
        }
    }
    __syncthreads();                      // row-tile complete (both co-halves)
    const int p8 = lane >> 3;
    const int ch = lane & 7;
#pragma unroll
    for (int it = 0; it < 4; ++it) {
        int px = mh * 32 + it * 8 + p8;   // wave covers its 32-px half of the row
        uint4 v = *(const uint4*)(RT + px * 64 + ((ch ^ (px & 7)) << 3));
        *(uint4*)(out + (((size_t)y * W + x0 + px) * 64 + ch * 8)) = v;
    }
}

// ---------------- sepconv via MFMA band-matmul, f32 img staging, z = batch ----------
__global__ __launch_bounds__(256, 2)
void sepconv3(const float* __restrict__ img,
              const uint16_t* __restrict__ kvT, const uint16_t* __restrict__ khT,
              float* __restrict__ out, int accum) {
    __shared__ uint4 SB[320 * 8];
    __shared__ float SC[4][16 * 83];
    const int y = blockIdx.x, c = blockIdx.y, z = blockIdx.z;
    const int tid = threadIdx.x, lane = tid & 63, wv = tid >> 6;
    const float* ip = img + (size_t)(z * 3 + c) * HIMG * WIMG;
    kvT += (size_t)z * 4 * CHAIN;
    khT += (size_t)z * 4 * CHAIN;

    for (int task = tid; task < 40 * 64; task += 256) {
        int i = task & 63;
        int u0 = (task >> 6) * 8;
        float f[8];
        bool rowok = (i <= 50);
        const float* rp = ip + (size_t)(y + i) * WIMG;
#pragma unroll
        for (int e2 = 0; e2 < 4; ++e2) {
            int u = u0 + e2 * 2;
            float2 v2 = (rowok && u < WIMG) ? *(const float2*)(rp + u) : float2{0.f, 0.f};
            f[e2 * 2] = v2.x; f[e2 * 2 + 1] = v2.y;
        }
#pragma unroll
        for (int e = 0; e < 8; ++e) {
            int u = u0 + e;
            *((ushort*)SB + u * 64 + (((i >> 3) ^ (u & 7)) << 3) + (i & 7)) = f2bf(f[e]);
        }
    }
    __syncthreads();

    const int l4 = lane & 15, g = lane >> 4;
    for (int xt = 0; xt < 4; ++xt) {
        const int x0 = (wv * 4 + xt) * 16;
        const int xpix = x0 + l4;
        bhalf8 a0 = *(const bhalf8*)(kvT + ((size_t)y * W + xpix) * 64 + g * 8);
        bhalf8 a1 = *(const bhalf8*)(kvT + ((size_t)y * W + xpix) * 64 + 32 + g * 8);
        f32x4 acc[5];
#pragma unroll
        for (int nt = 0; nt < 5; ++nt) acc[nt] = (f32x4){0.f, 0.f, 0.f, 0.f};
#pragma unroll
        for (int nt = 0; nt < 5; ++nt) {
            int u = x0 + nt * 16 + l4;
            bhalf8 b0 = *(const bhalf8*)((ushort*)SB + u * 64 + ((g ^ (u & 7)) << 3));
            acc[nt] = __builtin_amdgcn_mfma_f32_16x16x32_bf16(a0, b0, acc[nt], 0, 0, 0);
            bhalf8 b1 = *(const bhalf8*)((ushort*)SB + u * 64 + (((4 + g) ^ (u & 7)) << 3));
            acc[nt] = __builtin_amdgcn_mfma_f32_16x16x32_bf16(a1, b1, acc[nt], 0, 0, 0);
        }
#pragma unroll
        for (int nt = 0; nt < 5; ++nt)
#pragma unroll
            for (int r = 0; r < 4; ++r)
                SC[wv][(g * 4 + r) * 83 + nt * 16 + l4] = acc[nt][r];

        const uint16_t* khp = khT + ((size_t)y * W + xpix) * 64;
        float partial = 0.f;
#pragma unroll
        for (int jj = 0; jj < 13; ++jj) {
            int j = g * 13 + jj;
            if (j < KK)
                partial = fmaf(SC[wv][l4 * 83 + l4 + j], bf2f(khp[j]), partial);
        }
        partial += __shfl_xor(partial, 16);
        partial += __shfl_xor(partial, 32);
        if (g == 0) {
            size_t oi = ((size_t)(z * 3 + c) * H + y) * W + xpix;
            if (accum) out[oi] += partial;
            else       out[oi] = partial;
        }
    }
}

extern "C" void kernel_launch(void* const* d_in, const int* in_sizes, int n_in,
                              void* d_out, int out_size, void* d_ws, size_t ws_size,
                              hipStream_t stream) {
    const float* x  = (const float*)d_in[0];
    const float* i1 = (const float*)d_in[1];
    const float* i2 = (const float*)d_in[2];
    const float* W1 = (const float*)d_in[3];
    const float* B1 = (const float*)d_in[4];
    const float* W2 = (const float*)d_in[5];
    const float* B2 = (const float*)d_in[6];
    const float* W3 = (const float*)d_in[7];
    const float* B3 = (const float*)d_in[8];
    float* out = (float*)d_out;

    char* wsb = (char*)d_ws;
    const size_t IMGB = CHAIN * 2;               // 8,388,608 B per bf16 image
    const size_t WPN  = 4 * 9 * 4 * 2 * 64 * 8;  // elems per wp layer

    // weight-prep tables live in d_out (884,736 B << 3.1 MB); fully consumed by the conv
    // layers before sepconv overwrites d_out (stream-ordered, race-free).
    uint16_t* wp1 = (uint16_t*)d_out;
    uint16_t* wp2 = wp1 + WPN;
    uint16_t* wp3 = wp2 + WPN;
    wprep<<<72, 256, 0, stream>>>(W1, wp1, CF);
    wprep<<<72, 256, 0, stream>>>(W2, wp2, KK);
    wprep<<<72, 256, 0, stream>>>(W3, wp3, KK);

    if (ws_size >= 32 * IMGB) {
        // ---- fully batch-merged: A/B ping-pong of 16 images each (exactly 256 MiB)
        uint16_t* A   = (uint16_t*)wsb;
        uint16_t* Bb  = (uint16_t*)(wsb + 16 * IMGB);
        uint16_t* upT = Bb + 12 * CHAIN;         // upT in B[12..16), dead after layer 1

        upsample_cvt<<<dim3(H, 8, BB), 256, 0, stream>>>(x, upT);
        conv_mfma<<<dim3(64 * 4 * 16), 512, 0, stream>>>(upT, wp1, B1, A, 0, CHAIN, 0);
        conv_mfma<<<dim3(64 * 4 * 16), 512, 0, stream>>>(A,  wp2, B2, Bb, CHAIN, 4 * CHAIN, 0);
        conv_mfma<<<dim3(64 * 4 * 16), 512, 0, stream>>>(Bb, wp3, B3, A,  CHAIN, 4 * CHAIN, 0);
        sepconv3<<<dim3(H, 3, BB), 256, 0, stream>>>(i1, A,             A + CHAIN,     out, 0);
        sepconv3<<<dim3(H, 3, BB), 256, 0, stream>>>(i2, A + 2 * CHAIN, A + 3 * CHAIN, out, 1);
    } else if (ws_size >= 13 * IMGB) {
        // ---- per-batch fallback (109 MB)
        uint16_t* r1  = (uint16_t*)wsb;
        uint16_t* r2  = (uint16_t*)(wsb + 4 * IMGB);
        uint16_t* r3  = (uint16_t*)(wsb + 8 * IMGB);
        uint16_t* upT = (uint16_t*)(wsb + 12 * IMGB);
        for (int b = 0; b < BB; ++b) {
            upsample_cvt<<<dim3(H, 8, 1), 256, 0, stream>>>(x + (size_t)b * CF * HH * HH, upT);
            conv_mfma<<<dim3(64 * 4 * 4), 512, 0, stream>>>(upT, wp1, B1, r1, 0, 0, 0);
            conv_mfma<<<dim3(64 * 4 * 4), 512, 0, stream>>>(r1, wp2, B2, r2, CHAIN, 0, 0);
            conv_mfma<<<dim3(64 * 4 * 4), 512, 0, stream>>>(r2, wp3, B3, r3, CHAIN, 0, 0);
            for (int p = 0; p < 2; ++p) {
                const float* img = (p ? i2 : i1) + (size_t)b * 3 * HIMG * WIMG;
                sepconv3<<<dim3(H, 3, 1), 256, 0, stream>>>(img,
                        r3 + (size_t)(2 * p) * CHAIN, r3 + (size_t)(2 * p + 1) * CHAIN,
                        out + (size_t)b * 3 * HWN, p);
            }
        }
    } else {
        // ---- minimal (59 MB): per (batch, phase), 2-chain dispatches
        uint16_t* upT = (uint16_t*)wsb;
        uint16_t* t1  = (uint16_t*)(wsb + 1 * IMGB);
        uint16_t* t2  = (uint16_t*)(wsb + 3 * IMGB);
        uint16_t* t3  = (uint16_t*)(wsb + 5 * IMGB);
        for (int b = 0; b < BB; ++b) {
            upsample_cvt<<<dim3(H, 8, 1), 256, 0, stream>>>(x + (size_t)b * CF * HH * HH, upT);
            for (int p = 0; p < 2; ++p) {
                conv_mfma<<<dim3(64 * 4 * 2), 512, 0, stream>>>(upT, wp1, B1, t1, 0, 0, 2 * p);
                conv_mfma<<<dim3(64 * 4 * 2), 512, 0, stream>>>(t1, wp2, B2, t2, CHAIN, 0, 2 * p);
                conv_mfma<<<dim3(64 * 4 * 2), 512, 0, stream>>>(t2, wp3, B3, t3, CHAIN, 0, 2 * p);
                const float* img = (p ? i2 : i1) + (size_t)b * 3 * HIMG * WIMG;
                sepconv3<<<dim3(H, 3, 1), 256, 0, stream>>>(img, t3, t3 + CHAIN,
                        out + (size_t)b * 3 * HWN, p);
            }
        }
    }
}